// Round 2
// baseline (1385.719 us; speedup 1.0000x reference)
//
#include <hip/hip_runtime.h>
#include <cstdint>

typedef _Float16 f16;
typedef _Float16 f16x8 __attribute__((ext_vector_type(8)));
typedef _Float16 f16x4 __attribute__((ext_vector_type(4)));
typedef float f32x4 __attribute__((ext_vector_type(4)));

#define AS1 __attribute__((address_space(1)))
#define AS3 __attribute__((address_space(3)))

// B=2, L=2048, H=16, Dk=64, D=1024
#define LSEQ 2048
#define NH 16
#define DKH 64
#define DMOD 1024
#define MROWS 4096  // B*L

__device__ __forceinline__ void load16_lds(const void* g, void* l) {
  __builtin_amdgcn_global_load_lds((const AS1 uint32_t*)g, (AS3 uint32_t*)l, 16, 0, 0);
}

// ---------------- fp32 -> fp16 convert (7 tensors) ----------------
__global__ __launch_bounds__(256) void cvt_kernel(
    const float* __restrict__ q, const float* __restrict__ k, const float* __restrict__ v,
    const float* __restrict__ wq, const float* __restrict__ wk, const float* __restrict__ wv,
    const float* __restrict__ wo,
    f16* __restrict__ oq, f16* __restrict__ ok, f16* __restrict__ ov,
    f16* __restrict__ owq, f16* __restrict__ owk, f16* __restrict__ owv, f16* __restrict__ owo) {
  const float* src; f16* dst; int n;
  switch (blockIdx.y) {
    case 0: src = q;  dst = oq;  n = MROWS * DMOD; break;
    case 1: src = k;  dst = ok;  n = MROWS * DMOD; break;
    case 2: src = v;  dst = ov;  n = MROWS * DMOD; break;
    case 3: src = wq; dst = owq; n = DMOD * DMOD;  break;
    case 4: src = wk; dst = owk; n = DMOD * DMOD;  break;
    case 5: src = wv; dst = owv; n = DMOD * DMOD;  break;
    default: src = wo; dst = owo; n = DMOD * DMOD; break;
  }
  int i = (blockIdx.x * 256 + threadIdx.x) * 4;
  if (i < n) {
    float4 f = *(const float4*)(src + i);
    f16x4 h = {(f16)f.x, (f16)f.y, (f16)f.z, (f16)f.w};
    *(f16x4*)(dst + i) = h;
  }
}

// ---------------- mask int32 -> bit pack ----------------
__global__ __launch_bounds__(256) void maskpack_kernel(const int* __restrict__ mask,
                                                       unsigned long long* __restrict__ bits) {
  int i = blockIdx.x * 256 + threadIdx.x;
  unsigned long long b = __ballot(mask[i] != 0);
  if ((threadIdx.x & 63) == 0) bits[i >> 6] = b;
}

// ---------------- GEMM: C[m,n] = sum_k A[m,k]*Bt[n,k] + bias[n] ----------------
// M,N divisible by 128; K=1024. m97-style: global_load_lds w16, 2-barrier K-loop.
template <typename OutT>
__device__ __forceinline__ void gemm_body(const f16* __restrict__ A, const f16* __restrict__ Bt,
                                          const float* __restrict__ bias, OutT* __restrict__ C) {
  constexpr int K = 1024, NLD = 1024;
  __shared__ __align__(16) f16 As[128 * 32];
  __shared__ __align__(16) f16 Bs[128 * 32];
  const int tid = threadIdx.x, lane = tid & 63, w = tid >> 6;
  const int m0 = blockIdx.x * 128, n0 = blockIdx.y * 128;
  const int wm = (w >> 1) * 64, wn = (w & 1) * 64;
  f32x4 acc[4][4] = {};
  const int e0 = (w * 2 + 0) * 64 + lane;   // 16B-chunk ids into [128][32] tile
  const int e1 = (w * 2 + 1) * 64 + lane;
  const f16* ga0 = A + (size_t)(m0 + (e0 >> 2)) * K + (e0 & 3) * 8;
  const f16* ga1 = A + (size_t)(m0 + (e1 >> 2)) * K + (e1 & 3) * 8;
  const f16* gb0 = Bt + (size_t)(n0 + (e0 >> 2)) * K + (e0 & 3) * 8;
  const f16* gb1 = Bt + (size_t)(n0 + (e1 >> 2)) * K + (e1 & 3) * 8;
  f16* lA0 = As + (w * 2 + 0) * 512;  // wave-uniform LDS bases
  f16* lA1 = As + (w * 2 + 1) * 512;
  f16* lB0 = Bs + (w * 2 + 0) * 512;
  f16* lB1 = Bs + (w * 2 + 1) * 512;
  for (int kt = 0; kt < K; kt += 32) {
    __syncthreads();
    load16_lds(ga0 + kt, lA0);
    load16_lds(ga1 + kt, lA1);
    load16_lds(gb0 + kt, lB0);
    load16_lds(gb1 + kt, lB1);
    __syncthreads();
    f16x8 af[4], bf[4];
#pragma unroll
    for (int mt = 0; mt < 4; ++mt)
      af[mt] = *(const f16x8*)(As + (wm + mt * 16 + (lane & 15)) * 32 + (lane >> 4) * 8);
#pragma unroll
    for (int nt = 0; nt < 4; ++nt)
      bf[nt] = *(const f16x8*)(Bs + (wn + nt * 16 + (lane & 15)) * 32 + (lane >> 4) * 8);
#pragma unroll
    for (int mt = 0; mt < 4; ++mt)
#pragma unroll
      for (int nt = 0; nt < 4; ++nt)
        acc[mt][nt] = __builtin_amdgcn_mfma_f32_16x16x32_f16(af[mt], bf[nt], acc[mt][nt], 0, 0, 0);
  }
  const int cn = lane & 15, rg = lane >> 4;
#pragma unroll
  for (int nt = 0; nt < 4; ++nt) {
    int n = n0 + wn + nt * 16 + cn;
    float bv = bias[n];
#pragma unroll
    for (int mt = 0; mt < 4; ++mt)
#pragma unroll
      for (int r = 0; r < 4; ++r) {
        int m = m0 + wm + mt * 16 + rg * 4 + r;
        C[(size_t)m * NLD + n] = (OutT)(acc[mt][nt][r] + bv);
      }
  }
}

__global__ __launch_bounds__(256) void gemm_qkv_kernel(
    const f16* A0, const f16* A1, const f16* A2,
    const f16* B0, const f16* B1, const f16* B2,
    const float* c0, const float* c1, const float* c2,
    f16* O0, f16* O1, f16* O2) {
  const f16* A; const f16* Bt; const float* bias; f16* O;
  if (blockIdx.z == 0)      { A = A0; Bt = B0; bias = c0; O = O0; }
  else if (blockIdx.z == 1) { A = A1; Bt = B1; bias = c1; O = O1; }
  else                      { A = A2; Bt = B2; bias = c2; O = O2; }
  gemm_body<f16>(A, Bt, bias, O);
}

__global__ __launch_bounds__(256) void gemm_out_kernel(const f16* __restrict__ A,
                                                       const f16* __restrict__ Bt,
                                                       const float* __restrict__ bias,
                                                       float* __restrict__ C) {
  gemm_body<float>(A, Bt, bias, C);
}

// ---------------- RoPE: (B,L,H,64) -> rotated (B,H,L,64) ----------------
__global__ __launch_bounds__(256) void rope_kernel(const f16* __restrict__ qin, const f16* __restrict__ kin,
                                                   f16* __restrict__ qout, f16* __restrict__ kout) {
  int t = blockIdx.x * 256 + threadIdx.x;  // B*L*H*32 = 2,097,152
  int i = t & 31;
  int h = (t >> 5) & 15;
  int l = (t >> 9) & 2047;
  int b = t >> 20;
  const f16* src = (blockIdx.y == 0) ? qin : kin;
  f16* dst = (blockIdx.y == 0) ? qout : kout;
  size_t inb = (((size_t)(b * 2048 + l)) * 16 + h) * 64;
  float a = (float)src[inb + i];
  float c2 = (float)src[inb + 32 + i];
  float invf = powf(10000.0f, -(float)i * (1.0f / 32.0f));
  float fr = (float)l * invf;
  float cs = cosf(fr), sn = sinf(fr);
  size_t outb = (((size_t)(b * 16 + h)) * 2048 + l) * 64;
  dst[outb + i]      = (f16)(a * cs - c2 * sn);
  dst[outb + 32 + i] = (f16)(c2 * cs + a * sn);
}

// ---------------- V transpose: (B,L,H,64) -> (B,H,64,L) ----------------
__global__ __launch_bounds__(256) void vtrans_kernel(const f16* __restrict__ vin, f16* __restrict__ vout) {
  __shared__ f16 tile[64][72];
  int bh = blockIdx.y;              // b*16+h
  int b = bh >> 4, h = bh & 15;
  int l0 = blockIdx.x * 64;
  int t = threadIdx.x;
#pragma unroll
  for (int j = 0; j < 16; ++j) {
    int e = t + 256 * j;            // 0..4095
    int l = e >> 6, d = e & 63;
    tile[d][l] = vin[(((size_t)(b * 2048 + l0 + l)) * 16 + h) * 64 + d];
  }
  __syncthreads();
#pragma unroll
  for (int j = 0; j < 16; ++j) {
    int e = t + 256 * j;
    int d = e >> 6, l = e & 63;
    vout[((size_t)(b * 16 + h) * 64 + d) * 2048 + l0 + l] = tile[d][l];
  }
}

// ---------------- fused attention ----------------
// block = (b, h, 8 q rows). 4 waves, wave w owns keys [w*512, w*512+512).
// Same per-iteration structure as the proven 16-row kernel: one 16-key tile per
// iteration (2 MFMAs), Q columns replicated Q[col&7]; postprocess (bias, mask,
// LDS store) predicated on qi<8 where q = qi directly.
// LDS: S = 8x2048 fp16 logits, layout [chunk=k/8][q=8][8] (32 KB) + 256B scratch.
__global__ __launch_bounds__(256, 4) void attn_kernel(
    const f16* __restrict__ qr, const f16* __restrict__ kr, const f16* __restrict__ vt,
    const float* __restrict__ bias, const unsigned int* __restrict__ mbits,
    float* __restrict__ wout, f16* __restrict__ attnout) {
  __shared__ __align__(16) f16 S[256 * 64];   // 32 KB
  __shared__ float red[64];                   // [0:32) wave maxes, [32:64) wave sums

  int bid = blockIdx.x;
  int b = bid & 1, qt = (bid >> 1) & 255, h = bid >> 9;
  int q0 = qt * 8;
  int tid = threadIdx.x, lane = tid & 63, w = tid >> 6;

  const f16* Qp = qr + (((size_t)(b * 16 + h)) * 2048 + q0) * 64;
  const f16* Kp = kr + ((size_t)(b * 16 + h)) * 2048 * 64;
  const f16* Vp = vt + ((size_t)(b * 16 + h)) * 64 * 2048;
  const float* brow = bias + ((size_t)h * 2048 + q0) * 2048;
  const unsigned int* mrow = mbits + ((size_t)(b * 2048 + q0)) * 64;
  float* Wrow = wout + (((size_t)(b * 16 + h)) * 2048 + q0) * 2048;

  const int qi = lane & 15, kg = lane >> 4;
  const int qq = qi & 7;   // Q row this lane's B-column carries (2x replication)
  f16x8 qf0 = *(const f16x8*)(Qp + qq * 64 + kg * 8);
  f16x8 qf1 = *(const f16x8*)(Qp + qq * 64 + kg * 8 + 32);

  float lmax = -3.0e38f;
  // ---- QK^T: D rows = keys, cols = q (cols 8..15 duplicate 0..7)
  for (int it = 0; it < 32; ++it) {
    int k0 = w * 512 + it * 16;
    f16x8 alo = *(const f16x8*)(Kp + (size_t)(k0 + qi) * 64 + kg * 8);
    f16x8 ahi = *(const f16x8*)(Kp + (size_t)(k0 + qi) * 64 + kg * 8 + 32);
    f32x4 a = {0.f, 0.f, 0.f, 0.f};
    a = __builtin_amdgcn_mfma_f32_16x16x32_f16(alo, qf0, a, 0, 0, 0);
    a = __builtin_amdgcn_mfma_f32_16x16x32_f16(ahi, qf1, a, 0, 0, 0);
    if (qi < 8) {                            // q = qi, keys k0 + kg*4 .. +3
      int kk = k0 + kg * 4;
      float4 b4 = *(const float4*)(brow + (size_t)qi * 2048 + kk);
      unsigned int mword = mrow[qi * 64 + (kk >> 5)];
      float v0, v1, v2, v3;
      v0 = ((mword >> ((kk & 31) + 0)) & 1u) ? a[0] * 0.125f + b4.x : -30000.0f;
      v1 = ((mword >> ((kk & 31) + 1)) & 1u) ? a[1] * 0.125f + b4.y : -30000.0f;
      v2 = ((mword >> ((kk & 31) + 2)) & 1u) ? a[2] * 0.125f + b4.z : -30000.0f;
      v3 = ((mword >> ((kk & 31) + 3)) & 1u) ? a[3] * 0.125f + b4.w : -30000.0f;
      lmax = fmaxf(fmaxf(lmax, fmaxf(v0, v1)), fmaxf(v2, v3));
      f16x4 hv = {(f16)v0, (f16)v1, (f16)v2, (f16)v3};
      *(f16x4*)(S + (kk >> 3) * 64 + qi * 8 + (kk & 4)) = hv;
    }
  }
  // wave max per q: group = lanes sharing lane&7 (inactive lanes hold -3e38)
  lmax = fmaxf(lmax, __shfl_xor(lmax, 8, 64));
  lmax = fmaxf(lmax, __shfl_xor(lmax, 16, 64));
  lmax = fmaxf(lmax, __shfl_xor(lmax, 32, 64));
  if (lane < 8) red[w * 8 + lane] = lmax;
  __syncthreads();

  // ---- pass 2: row sums. thread: q = tid&7, chunk group c2 = tid>>3
  const int q2 = tid & 7, c2 = tid >> 3;
  float m = fmaxf(fmaxf(red[q2], red[8 + q2]), fmaxf(red[16 + q2], red[24 + q2]));
  float psum = 0.f;
#pragma unroll
  for (int i = 0; i < 8; ++i) {
    int chunk = c2 + (i << 5);
    f16x8 hv = *(const f16x8*)(S + chunk * 64 + q2 * 8);
#pragma unroll
    for (int j = 0; j < 8; ++j) psum += __expf((float)hv[j] - m);
  }
  psum += __shfl_xor(psum, 8, 64);
  psum += __shfl_xor(psum, 16, 64);
  psum += __shfl_xor(psum, 32, 64);
  if (lane < 8) red[32 + w * 8 + lane] = psum;
  __syncthreads();
  float denom = red[32 + q2] + red[40 + q2] + red[48 + q2] + red[56 + q2];
  float rinv = 1.0f / denom;

  // ---- pass 3: write normalized weights (fp32, coalesced) + overwrite S with P
#pragma unroll 2
  for (int i = 0; i < 8; ++i) {
    int chunk = c2 + (i << 5);
    f16* sp = S + chunk * 64 + q2 * 8;
    f16x8 hv = *(const f16x8*)sp;
    float e0 = __expf((float)hv[0] - m) * rinv;
    float e1 = __expf((float)hv[1] - m) * rinv;
    float e2 = __expf((float)hv[2] - m) * rinv;
    float e3 = __expf((float)hv[3] - m) * rinv;
    float e4 = __expf((float)hv[4] - m) * rinv;
    float e5 = __expf((float)hv[5] - m) * rinv;
    float e6 = __expf((float)hv[6] - m) * rinv;
    float e7 = __expf((float)hv[7] - m) * rinv;
    float4 o0 = {e0, e1, e2, e3};
    float4 o1 = {e4, e5, e6, e7};
    *(float4*)(Wrow + (size_t)q2 * 2048 + chunk * 8) = o0;
    *(float4*)(Wrow + (size_t)q2 * 2048 + chunk * 8 + 4) = o1;
    f16x8 he = {(f16)e0, (f16)e1, (f16)e2, (f16)e3, (f16)e4, (f16)e5, (f16)e6, (f16)e7};
    *(f16x8*)sp = he;
  }
  __syncthreads();

  // ---- PV: A = P (rows replicated P[m&7]), B = Vt rows (contiguous 16B loads)
  f32x4 oacc[4] = {};
#pragma unroll 4
  for (int kt = 0; kt < 16; ++kt) {
    int kbase = w * 512 + kt * 32;
    f16x8 af = *(const f16x8*)(S + ((kbase >> 3) + kg) * 64 + qq * 8);
#pragma unroll
    for (int nt = 0; nt < 4; ++nt) {
      f16x8 bv = *(const f16x8*)(Vp + (size_t)(nt * 16 + qi) * 2048 + kbase + kg * 8);
      oacc[nt] = __builtin_amdgcn_mfma_f32_16x16x32_f16(af, bv, oacc[nt], 0, 0, 0);
    }
  }
  __syncthreads();  // logits dead; reuse LDS for O reduction
  float* Ob = (float*)S;  // [4 waves][8 q][68]
  if (kg < 2) {           // D rows m: q = (kg&1)*4 + r; kg=2,3 duplicate kg=0,1
#pragma unroll
    for (int nt = 0; nt < 4; ++nt)
#pragma unroll
      for (int r = 0; r < 4; ++r)
        Ob[(w * 8 + kg * 4 + r) * 68 + nt * 16 + qi] = oacc[nt][r];
  }
  __syncthreads();
  // final: wave w reduces q rows w*2, w*2+1 across 4 wave-partials; lane = dim
#pragma unroll
  for (int r2 = 0; r2 < 2; ++r2) {
    int q = w * 2 + r2;
    float s = 0.f;
#pragma unroll
    for (int w4 = 0; w4 < 4; ++w4) s += Ob[(w4 * 8 + q) * 68 + lane];
    attnout[((size_t)(b * 2048 + q0 + q)) * 1024 + h * 64 + lane] = (f16)s;
  }
}

// ---------------- launch ----------------
extern "C" void kernel_launch(void* const* d_in, const int* in_sizes, int n_in,
                              void* d_out, int out_size, void* d_ws, size_t ws_size,
                              hipStream_t stream) {
  const float* q    = (const float*)d_in[0];
  const float* k    = (const float*)d_in[1];
  const float* v    = (const float*)d_in[2];
  const int*   mask = (const int*)d_in[3];
  const float* bias = (const float*)d_in[4];
  const float* Wq = (const float*)d_in[5];  const float* bq = (const float*)d_in[6];
  const float* Wk = (const float*)d_in[7];  const float* bk = (const float*)d_in[8];
  const float* Wv = (const float*)d_in[9];  const float* bv = (const float*)d_in[10];
  const float* Wo = (const float*)d_in[11]; const float* bo = (const float*)d_in[12];
  float* out  = (float*)d_out;
  float* wout = out + (size_t)MROWS * DMOD;  // weights after out (4,194,304 floats)

  char* ws = (char*)d_ws;
  const size_t MB = 1u << 20;
  f16* qf   = (f16*)(ws + 0 * MB);    // fp16 query; reused as q_rot (B,H,L,64)
  f16* kf   = (f16*)(ws + 8 * MB);    // fp16 key;   reused as k_rot
  f16* vf   = (f16*)(ws + 16 * MB);   // fp16 value; reused as Vt (B,H,64,L)
  f16* wq16 = (f16*)(ws + 24 * MB);
  f16* wk16 = (f16*)(ws + 26 * MB);
  f16* wv16 = (f16*)(ws + 28 * MB);
  f16* wo16 = (f16*)(ws + 30 * MB);
  f16* qhat = (f16*)(ws + 32 * MB);   // q proj (B,L,H,64); reused as attn (B,L,1024)
  f16* khat = (f16*)(ws + 40 * MB);
  f16* vhat = (f16*)(ws + 48 * MB);
  unsigned long long* mbits = (unsigned long long*)(ws + 56 * MB);
  f16* qrot = qf; f16* krot = kf; f16* vtr = vf; f16* attnf = qhat;

  dim3 blk(256);
  cvt_kernel<<<dim3(4096, 7), blk, 0, stream>>>(q, k, v, Wq, Wk, Wv, Wo,
                                                qf, kf, vf, wq16, wk16, wv16, wo16);
  maskpack_kernel<<<dim3(32768), blk, 0, stream>>>(mask, mbits);
  gemm_qkv_kernel<<<dim3(32, 8, 3), blk, 0, stream>>>(qf, kf, vf, wq16, wk16, wv16,
                                                      bq, bk, bv, qhat, khat, vhat);
  rope_kernel<<<dim3(8192, 2), blk, 0, stream>>>(qhat, khat, qrot, krot);
  vtrans_kernel<<<dim3(32, 32), blk, 0, stream>>>(vhat, vtr);
  attn_kernel<<<dim3(8192), blk, 0, stream>>>(qrot, krot, vtr, bias,
                                              (const unsigned int*)mbits, wout, attnf);
  gemm_out_kernel<<<dim3(32, 8, 1), blk, 0, stream>>>(attnf, wo16, bo, out);
}

// Round 3
// 1192.396 us; speedup vs baseline: 1.1621x; 1.1621x over previous
//
#include <hip/hip_runtime.h>
#include <cstdint>

typedef _Float16 f16;
typedef _Float16 f16x8 __attribute__((ext_vector_type(8)));
typedef _Float16 f16x4 __attribute__((ext_vector_type(4)));
typedef float f32x4 __attribute__((ext_vector_type(4)));

#define AS1 __attribute__((address_space(1)))
#define AS3 __attribute__((address_space(3)))

// B=2, L=2048, H=16, Dk=64, D=1024
#define LSEQ 2048
#define NH 16
#define DKH 64
#define DMOD 1024
#define MROWS 4096  // B*L

__device__ __forceinline__ void load16_lds(const void* g, void* l) {
  __builtin_amdgcn_global_load_lds((const AS1 uint32_t*)g, (AS3 uint32_t*)l, 16, 0, 0);
}

// ---------------- fp32 -> fp16 convert (7 tensors) ----------------
__global__ __launch_bounds__(256) void cvt_kernel(
    const float* __restrict__ q, const float* __restrict__ k, const float* __restrict__ v,
    const float* __restrict__ wq, const float* __restrict__ wk, const float* __restrict__ wv,
    const float* __restrict__ wo,
    f16* __restrict__ oq, f16* __restrict__ ok, f16* __restrict__ ov,
    f16* __restrict__ owq, f16* __restrict__ owk, f16* __restrict__ owv, f16* __restrict__ owo) {
  const float* src; f16* dst; int n;
  switch (blockIdx.y) {
    case 0: src = q;  dst = oq;  n = MROWS * DMOD; break;
    case 1: src = k;  dst = ok;  n = MROWS * DMOD; break;
    case 2: src = v;  dst = ov;  n = MROWS * DMOD; break;
    case 3: src = wq; dst = owq; n = DMOD * DMOD;  break;
    case 4: src = wk; dst = owk; n = DMOD * DMOD;  break;
    case 5: src = wv; dst = owv; n = DMOD * DMOD;  break;
    default: src = wo; dst = owo; n = DMOD * DMOD; break;
  }
  int i = (blockIdx.x * 256 + threadIdx.x) * 4;
  if (i < n) {
    float4 f = *(const float4*)(src + i);
    f16x4 h = {(f16)f.x, (f16)f.y, (f16)f.z, (f16)f.w};
    *(f16x4*)(dst + i) = h;
  }
}

// ---------------- mask int32 -> bit pack ----------------
__global__ __launch_bounds__(256) void maskpack_kernel(const int* __restrict__ mask,
                                                       unsigned long long* __restrict__ bits) {
  int i = blockIdx.x * 256 + threadIdx.x;
  unsigned long long b = __ballot(mask[i] != 0);
  if ((threadIdx.x & 63) == 0) bits[i >> 6] = b;
}

// ---------------- GEMM: C[m,n] = sum_k A[m,k]*Bt[n,k] + bias[n] ----------------
// M,N divisible by 128; K=1024. m97-style: global_load_lds w16, 2-barrier K-loop.
template <typename OutT>
__device__ __forceinline__ void gemm_body(const f16* __restrict__ A, const f16* __restrict__ Bt,
                                          const float* __restrict__ bias, OutT* __restrict__ C) {
  constexpr int K = 1024, NLD = 1024;
  __shared__ __align__(16) f16 As[128 * 32];
  __shared__ __align__(16) f16 Bs[128 * 32];
  const int tid = threadIdx.x, lane = tid & 63, w = tid >> 6;
  const int m0 = blockIdx.x * 128, n0 = blockIdx.y * 128;
  const int wm = (w >> 1) * 64, wn = (w & 1) * 64;
  f32x4 acc[4][4] = {};
  const int e0 = (w * 2 + 0) * 64 + lane;   // 16B-chunk ids into [128][32] tile
  const int e1 = (w * 2 + 1) * 64 + lane;
  const f16* ga0 = A + (size_t)(m0 + (e0 >> 2)) * K + (e0 & 3) * 8;
  const f16* ga1 = A + (size_t)(m0 + (e1 >> 2)) * K + (e1 & 3) * 8;
  const f16* gb0 = Bt + (size_t)(n0 + (e0 >> 2)) * K + (e0 & 3) * 8;
  const f16* gb1 = Bt + (size_t)(n0 + (e1 >> 2)) * K + (e1 & 3) * 8;
  f16* lA0 = As + (w * 2 + 0) * 512;  // wave-uniform LDS bases
  f16* lA1 = As + (w * 2 + 1) * 512;
  f16* lB0 = Bs + (w * 2 + 0) * 512;
  f16* lB1 = Bs + (w * 2 + 1) * 512;
  for (int kt = 0; kt < K; kt += 32) {
    __syncthreads();
    load16_lds(ga0 + kt, lA0);
    load16_lds(ga1 + kt, lA1);
    load16_lds(gb0 + kt, lB0);
    load16_lds(gb1 + kt, lB1);
    __syncthreads();
    f16x8 af[4], bf[4];
#pragma unroll
    for (int mt = 0; mt < 4; ++mt)
      af[mt] = *(const f16x8*)(As + (wm + mt * 16 + (lane & 15)) * 32 + (lane >> 4) * 8);
#pragma unroll
    for (int nt = 0; nt < 4; ++nt)
      bf[nt] = *(const f16x8*)(Bs + (wn + nt * 16 + (lane & 15)) * 32 + (lane >> 4) * 8);
#pragma unroll
    for (int mt = 0; mt < 4; ++mt)
#pragma unroll
      for (int nt = 0; nt < 4; ++nt)
        acc[mt][nt] = __builtin_amdgcn_mfma_f32_16x16x32_f16(af[mt], bf[nt], acc[mt][nt], 0, 0, 0);
  }
  const int cn = lane & 15, rg = lane >> 4;
#pragma unroll
  for (int nt = 0; nt < 4; ++nt) {
    int n = n0 + wn + nt * 16 + cn;
    float bv = bias[n];
#pragma unroll
    for (int mt = 0; mt < 4; ++mt)
#pragma unroll
      for (int r = 0; r < 4; ++r) {
        int m = m0 + wm + mt * 16 + rg * 4 + r;
        C[(size_t)m * NLD + n] = (OutT)(acc[mt][nt][r] + bv);
      }
  }
}

__global__ __launch_bounds__(256) void gemm_qkv_kernel(
    const f16* A0, const f16* A1, const f16* A2,
    const f16* B0, const f16* B1, const f16* B2,
    const float* c0, const float* c1, const float* c2,
    f16* O0, f16* O1, f16* O2) {
  const f16* A; const f16* Bt; const float* bias; f16* O;
  if (blockIdx.z == 0)      { A = A0; Bt = B0; bias = c0; O = O0; }
  else if (blockIdx.z == 1) { A = A1; Bt = B1; bias = c1; O = O1; }
  else                      { A = A2; Bt = B2; bias = c2; O = O2; }
  gemm_body<f16>(A, Bt, bias, O);
}

__global__ __launch_bounds__(256) void gemm_out_kernel(const f16* __restrict__ A,
                                                       const f16* __restrict__ Bt,
                                                       const float* __restrict__ bias,
                                                       float* __restrict__ C) {
  gemm_body<float>(A, Bt, bias, C);
}

// ---------------- RoPE: (B,L,H,64) -> rotated (B,H,L,64) ----------------
__global__ __launch_bounds__(256) void rope_kernel(const f16* __restrict__ qin, const f16* __restrict__ kin,
                                                   f16* __restrict__ qout, f16* __restrict__ kout) {
  int t = blockIdx.x * 256 + threadIdx.x;  // B*L*H*32 = 2,097,152
  int i = t & 31;
  int h = (t >> 5) & 15;
  int l = (t >> 9) & 2047;
  int b = t >> 20;
  const f16* src = (blockIdx.y == 0) ? qin : kin;
  f16* dst = (blockIdx.y == 0) ? qout : kout;
  size_t inb = (((size_t)(b * 2048 + l)) * 16 + h) * 64;
  float a = (float)src[inb + i];
  float c2 = (float)src[inb + 32 + i];
  float invf = powf(10000.0f, -(float)i * (1.0f / 32.0f));
  float fr = (float)l * invf;
  float cs = cosf(fr), sn = sinf(fr);
  size_t outb = (((size_t)(b * 16 + h)) * 2048 + l) * 64;
  dst[outb + i]      = (f16)(a * cs - c2 * sn);
  dst[outb + 32 + i] = (f16)(c2 * cs + a * sn);
}

// ---------------- V transpose: (B,L,H,64) -> (B,H,64,L) ----------------
__global__ __launch_bounds__(256) void vtrans_kernel(const f16* __restrict__ vin, f16* __restrict__ vout) {
  __shared__ f16 tile[64][72];
  int bh = blockIdx.y;              // b*16+h
  int b = bh >> 4, h = bh & 15;
  int l0 = blockIdx.x * 64;
  int t = threadIdx.x;
#pragma unroll
  for (int j = 0; j < 16; ++j) {
    int e = t + 256 * j;            // 0..4095
    int l = e >> 6, d = e & 63;
    tile[d][l] = vin[(((size_t)(b * 2048 + l0 + l)) * 16 + h) * 64 + d];
  }
  __syncthreads();
#pragma unroll
  for (int j = 0; j < 16; ++j) {
    int e = t + 256 * j;
    int d = e >> 6, l = e & 63;
    vout[((size_t)(b * 16 + h) * 64 + d) * 2048 + l0 + l] = tile[d][l];
  }
}

// ---------------- fused attention ----------------
// block = (b, h, 16 q rows). 4 waves, wave w owns keys [w*512, w*512+512) in QK/PV.
// S = 16x2048 fp16, layout [chunk=k/8][slot=q^(chunk&7)][8]  (64 KB, XOR-swizzled).
// Phase 1: raw scaled logits only (no bias/mask — no HBM dependency in QK loop).
// Phase 2 (wave-local, no barriers): thread (q=tid>>4, j=tid&15) owns chunks j+16i.
//   2a: coalesced bias stream + mask, track max; 2b: sum exp; 2c: weights + P store.
#define ATTN_LDS 65536
__global__ __launch_bounds__(256, 2) void attn_kernel(
    const f16* __restrict__ qr, const f16* __restrict__ kr, const f16* __restrict__ vt,
    const float* __restrict__ bias, const unsigned int* __restrict__ mbits,
    float* __restrict__ wout, f16* __restrict__ attnout) {
  extern __shared__ char smem[];
  f16* S = (f16*)smem;

  int bid = blockIdx.x;
  int b = bid & 1, qt = (bid >> 1) & 127, h = bid >> 8;
  int q0 = qt * 16;
  int tid = threadIdx.x, lane = tid & 63, w = tid >> 6;

  const f16* Qp = qr + (((size_t)(b * 16 + h)) * 2048 + q0) * 64;
  const f16* Kp = kr + ((size_t)(b * 16 + h)) * 2048 * 64;
  const f16* Vp = vt + ((size_t)(b * 16 + h)) * 64 * 2048;
  const float* brow = bias + ((size_t)h * 2048 + q0) * 2048;
  const unsigned int* mrow = mbits + ((size_t)(b * 2048 + q0)) * 64;
  float* Wrow = wout + (((size_t)(b * 16 + h)) * 2048 + q0) * 2048;

  const int qi = lane & 15, kg = lane >> 4;
  f16x8 qf0 = *(const f16x8*)(Qp + qi * 64 + kg * 8);
  f16x8 qf1 = *(const f16x8*)(Qp + qi * 64 + kg * 8 + 32);

  // ---- phase 1: QK^T raw (D rows = keys, cols = q), scaled, to swizzled S
#pragma unroll 2
  for (int it = 0; it < 32; ++it) {
    int k0 = w * 512 + it * 16;
    f16x8 alo = *(const f16x8*)(Kp + (size_t)(k0 + qi) * 64 + kg * 8);
    f16x8 ahi = *(const f16x8*)(Kp + (size_t)(k0 + qi) * 64 + kg * 8 + 32);
    f32x4 a = {0.f, 0.f, 0.f, 0.f};
    a = __builtin_amdgcn_mfma_f32_16x16x32_f16(alo, qf0, a, 0, 0, 0);
    a = __builtin_amdgcn_mfma_f32_16x16x32_f16(ahi, qf1, a, 0, 0, 0);
    int kk = k0 + kg * 4;
    int ch = kk >> 3;
    f16x4 hv = {(f16)(a[0] * 0.125f), (f16)(a[1] * 0.125f),
                (f16)(a[2] * 0.125f), (f16)(a[3] * 0.125f)};
    *(f16x4*)(S + ch * 128 + ((qi ^ (ch & 7)) * 8) + (kk & 4)) = hv;
  }
  __syncthreads();

  // ---- phase 2: per-thread row q = tid>>4 (one wave owns 4 rows), j = tid&15
  const int q = tid >> 4, j = tid & 15;
  const float* bq = brow + (size_t)q * 2048;
  const unsigned int* mq = mrow + q * 64;
  float* Wq_ = Wrow + (size_t)q * 2048;

  // 2a: v = s + bias (masked), coalesced bias stream, track max, store v back
  float vmax = -3.0e38f;
#pragma unroll 4
  for (int i = 0; i < 16; ++i) {
    int c = j + i * 16;
    f16* sp = S + c * 128 + ((q ^ (c & 7)) * 8);
    float4 b0 = *(const float4*)(bq + c * 8);
    float4 b1 = *(const float4*)(bq + c * 8 + 4);
    unsigned int mb = mq[c >> 2] >> ((c & 3) * 8);
    f16x8 s8 = *(const f16x8*)sp;
    float v0 = (mb & 1u)   ? (float)s8[0] + b0.x : -30000.0f;
    float v1 = (mb & 2u)   ? (float)s8[1] + b0.y : -30000.0f;
    float v2 = (mb & 4u)   ? (float)s8[2] + b0.z : -30000.0f;
    float v3 = (mb & 8u)   ? (float)s8[3] + b0.w : -30000.0f;
    float v4 = (mb & 16u)  ? (float)s8[4] + b1.x : -30000.0f;
    float v5 = (mb & 32u)  ? (float)s8[5] + b1.y : -30000.0f;
    float v6 = (mb & 64u)  ? (float)s8[6] + b1.z : -30000.0f;
    float v7 = (mb & 128u) ? (float)s8[7] + b1.w : -30000.0f;
    vmax = fmaxf(vmax, fmaxf(fmaxf(fmaxf(v0, v1), fmaxf(v2, v3)),
                             fmaxf(fmaxf(v4, v5), fmaxf(v6, v7))));
    f16x8 hv = {(f16)v0, (f16)v1, (f16)v2, (f16)v3, (f16)v4, (f16)v5, (f16)v6, (f16)v7};
    *(f16x8*)sp = hv;
  }
  // row max: the 16 threads of row q are one contiguous 16-lane group
  vmax = fmaxf(vmax, __shfl_xor(vmax, 1, 64));
  vmax = fmaxf(vmax, __shfl_xor(vmax, 2, 64));
  vmax = fmaxf(vmax, __shfl_xor(vmax, 4, 64));
  vmax = fmaxf(vmax, __shfl_xor(vmax, 8, 64));
  const float m = vmax;

  // 2b: row sum of exp
  float psum = 0.f;
#pragma unroll 4
  for (int i = 0; i < 16; ++i) {
    int c = j + i * 16;
    const f16* sp = S + c * 128 + ((q ^ (c & 7)) * 8);
    f16x8 v8 = *(const f16x8*)sp;
    psum += __expf((float)v8[0] - m) + __expf((float)v8[1] - m) +
            __expf((float)v8[2] - m) + __expf((float)v8[3] - m) +
            __expf((float)v8[4] - m) + __expf((float)v8[5] - m) +
            __expf((float)v8[6] - m) + __expf((float)v8[7] - m);
  }
  psum += __shfl_xor(psum, 1, 64);
  psum += __shfl_xor(psum, 2, 64);
  psum += __shfl_xor(psum, 4, 64);
  psum += __shfl_xor(psum, 8, 64);
  const float rinv = 1.0f / psum;

  // 2c: write normalized weights (fp32, coalesced) + overwrite S with P (fp16)
#pragma unroll 2
  for (int i = 0; i < 16; ++i) {
    int c = j + i * 16;
    f16* sp = S + c * 128 + ((q ^ (c & 7)) * 8);
    f16x8 v8 = *(const f16x8*)sp;
    float e0 = __expf((float)v8[0] - m) * rinv;
    float e1 = __expf((float)v8[1] - m) * rinv;
    float e2 = __expf((float)v8[2] - m) * rinv;
    float e3 = __expf((float)v8[3] - m) * rinv;
    float e4 = __expf((float)v8[4] - m) * rinv;
    float e5 = __expf((float)v8[5] - m) * rinv;
    float e6 = __expf((float)v8[6] - m) * rinv;
    float e7 = __expf((float)v8[7] - m) * rinv;
    float4 o0 = {e0, e1, e2, e3};
    float4 o1 = {e4, e5, e6, e7};
    *(float4*)(Wq_ + c * 8) = o0;
    *(float4*)(Wq_ + c * 8 + 4) = o1;
    f16x8 he = {(f16)e0, (f16)e1, (f16)e2, (f16)e3, (f16)e4, (f16)e5, (f16)e6, (f16)e7};
    *(f16x8*)sp = he;
  }
  __syncthreads();

  // ---- PV: A = P (from swizzled S), B = Vt rows (contiguous 16B loads)
  f32x4 oacc[4] = {};
#pragma unroll 4
  for (int kt = 0; kt < 16; ++kt) {
    int kbase = w * 512 + kt * 32;
    int ch = (kbase >> 3) + kg;
    f16x8 af = *(const f16x8*)(S + ch * 128 + ((qi ^ (ch & 7)) * 8));
#pragma unroll
    for (int nt = 0; nt < 4; ++nt) {
      f16x8 bv = *(const f16x8*)(Vp + (size_t)(nt * 16 + qi) * 2048 + kbase + kg * 8);
      oacc[nt] = __builtin_amdgcn_mfma_f32_16x16x32_f16(af, bv, oacc[nt], 0, 0, 0);
    }
  }
  __syncthreads();  // logits dead; reuse LDS for O reduction
  float* Ob = (float*)smem;  // [4][16][68]
#pragma unroll
  for (int nt = 0; nt < 4; ++nt)
#pragma unroll
    for (int r = 0; r < 4; ++r)
      Ob[(w * 16 + kg * 4 + r) * 68 + nt * 16 + qi] = oacc[nt][r];
  __syncthreads();
  int qv = tid >> 4, d0 = (tid & 15) * 4;
  float sx = 0.f, sy = 0.f, sz = 0.f, sw = 0.f;
#pragma unroll
  for (int w4 = 0; w4 < 4; ++w4) {
    const float* p = &Ob[(w4 * 16 + qv) * 68 + d0];
    sx += p[0]; sy += p[1]; sz += p[2]; sw += p[3];
  }
  f16x4 hs = {(f16)sx, (f16)sy, (f16)sz, (f16)sw};
  *(f16x4*)(attnout + ((size_t)(b * 2048 + q0 + qv)) * 1024 + h * 64 + d0) = hs;
}

// ---------------- launch ----------------
extern "C" void kernel_launch(void* const* d_in, const int* in_sizes, int n_in,
                              void* d_out, int out_size, void* d_ws, size_t ws_size,
                              hipStream_t stream) {
  const float* q    = (const float*)d_in[0];
  const float* k    = (const float*)d_in[1];
  const float* v    = (const float*)d_in[2];
  const int*   mask = (const int*)d_in[3];
  const float* bias = (const float*)d_in[4];
  const float* Wq = (const float*)d_in[5];  const float* bq = (const float*)d_in[6];
  const float* Wk = (const float*)d_in[7];  const float* bk = (const float*)d_in[8];
  const float* Wv = (const float*)d_in[9];  const float* bv = (const float*)d_in[10];
  const float* Wo = (const float*)d_in[11]; const float* bo = (const float*)d_in[12];
  float* out  = (float*)d_out;
  float* wout = out + (size_t)MROWS * DMOD;  // weights after out (4,194,304 floats)

  char* ws = (char*)d_ws;
  const size_t MB = 1u << 20;
  f16* qf   = (f16*)(ws + 0 * MB);    // fp16 query; reused as q_rot (B,H,L,64)
  f16* kf   = (f16*)(ws + 8 * MB);    // fp16 key;   reused as k_rot
  f16* vf   = (f16*)(ws + 16 * MB);   // fp16 value; reused as Vt (B,H,64,L)
  f16* wq16 = (f16*)(ws + 24 * MB);
  f16* wk16 = (f16*)(ws + 26 * MB);
  f16* wv16 = (f16*)(ws + 28 * MB);
  f16* wo16 = (f16*)(ws + 30 * MB);
  f16* qhat = (f16*)(ws + 32 * MB);   // q proj (B,L,H,64); reused as attn (B,L,1024)
  f16* khat = (f16*)(ws + 40 * MB);
  f16* vhat = (f16*)(ws + 48 * MB);
  unsigned long long* mbits = (unsigned long long*)(ws + 56 * MB);
  f16* qrot = qf; f16* krot = kf; f16* vtr = vf; f16* attnf = qhat;

  dim3 blk(256);
  cvt_kernel<<<dim3(4096, 7), blk, 0, stream>>>(q, k, v, Wq, Wk, Wv, Wo,
                                                qf, kf, vf, wq16, wk16, wv16, wo16);
  maskpack_kernel<<<dim3(32768), blk, 0, stream>>>(mask, mbits);
  gemm_qkv_kernel<<<dim3(32, 8, 3), blk, 0, stream>>>(qf, kf, vf, wq16, wk16, wv16,
                                                      bq, bk, bv, qhat, khat, vhat);
  rope_kernel<<<dim3(8192, 2), blk, 0, stream>>>(qhat, khat, qrot, krot);
  vtrans_kernel<<<dim3(32, 32), blk, 0, stream>>>(vhat, vtr);
  (void)hipFuncSetAttribute((const void*)attn_kernel,
                            hipFuncAttributeMaxDynamicSharedMemorySize, ATTN_LDS);
  attn_kernel<<<dim3(4096), blk, ATTN_LDS, stream>>>(qrot, krot, vtr, bias,
                                                     (const unsigned int*)mbits, wout, attnf);
  gemm_out_kernel<<<dim3(32, 8, 1), blk, 0, stream>>>(attnf, wo16, bo, out);
}